// Round 5
// baseline (1551.648 us; speedup 1.0000x reference)
//
#include <hip/hip_runtime.h>
#include <math.h>

// B=8, N=16, D=128, H=W=64 -> G=128 groups, K=4096 tokens/group.
// Algebra: keys GEMM collapses: attn_k = q_tilde . x_k + c with
// q_tilde = Wk^T(Wq mean + bq), c = query.bk. Logits ~ +-1 -> softmax
// without max-subtraction is safe. Two passes over x minimum.
//
// This version: ONE persistent cooperative kernel. 1024 resident blocks pull
// work items from global queues:
//   phase A: (g,s) mean-chunk items; last finisher of each group computes
//            query/qt/cvec inline and release-publishes ready[g].
//   phase B: (g,c) fused logit+exp+pool items; acquire-spin on ready[g].
// Group g's x slice is re-read by phase B shortly after phase A touched it
// (L2/L3-hot). Cross-block data exchange uses device-scope atomics only
// (per-XCD L2s are not cross-coherent).
#define G 128
#define D 128
#define K 4096
#define CK 64
#define ITEMS_A (G * 32)
#define ITEMS_B (G * 64)
#define NBLK_MAX 1024

#define LOADC(p) __hip_atomic_load((p), __ATOMIC_ACQUIRE, __HIP_MEMORY_SCOPE_AGENT)
#define STOREC(p, v) \
  __hip_atomic_store((p), (v), __ATOMIC_RELEASE, __HIP_MEMORY_SCOPE_AGENT)

union SMem {
  struct {  // phase A / inline-k2 side
    float mean_s[D];
    float query_s[D];
    float red2[256];
  } a;
  struct {  // phase B side (xs row stride 65 == 1 mod 32: conflict-free)
    float xs[D][CK + 1];
    float qs[D];
    float part_l[4][CK];
    float wsm[CK];
    float red[256];
  } b;
};

__global__ __launch_bounds__(256, 4) void fused_all(
    const float* __restrict__ x, const int* __restrict__ mask,
    const float* __restrict__ Wq, const float* __restrict__ bq,
    const float* __restrict__ Wk, const float* __restrict__ bk,
    float* meanacc, float* qt, float* cvec, float* oacc, float* denomv,
    int* ctrl, float* out) {
  __shared__ SMem sm;
  __shared__ int s_claim, s_old;
  __shared__ float s_cv;
  int* doneA = ctrl;
  int* doneB = ctrl + G;
  int* ready = ctrl + 2 * G;
  int* ctrA = ctrl + 3 * G;
  int* ctrB = ctrl + 3 * G + 1;
  const int tid = threadIdx.x;
  const int wid = tid >> 6, lane = tid & 63;

  // ---------------- Phase A: masked mean (+ inline query for last finisher)
  for (;;) {
    __syncthreads();
    if (tid == 0)
      s_claim = __hip_atomic_fetch_add(ctrA, 1, __ATOMIC_ACQ_REL,
                                       __HIP_MEMORY_SCOPE_AGENT);
    __syncthreads();
    const int item = s_claim;
    if (item >= ITEMS_A) break;
    const int g = item >> 5, s = item & 31;
    const int d = s * 4 + wid;  // one d-row per wave
    const float4* x4 = (const float4*)(x + ((size_t)g * D + d) * K);
    const int4* m4 = (const int4*)(mask + (size_t)g * K);
    float4 acc = make_float4(0.f, 0.f, 0.f, 0.f);
#pragma unroll
    for (int it = 0; it < K / 256; ++it) {  // 16 iters
      float4 a = x4[it * 64 + lane];
      int4 mi = m4[it * 64 + lane];  // L1/L2-hot (shared by 4 waves)
      acc.x += a.x * (float)mi.x;
      acc.y += a.y * (float)mi.y;
      acc.z += a.z * (float)mi.z;
      acc.w += a.w * (float)mi.w;
    }
    float sum = acc.x + acc.y + acc.z + acc.w;
#pragma unroll
    for (int o = 32; o > 0; o >>= 1) sum += __shfl_down(sum, o, 64);
    if (lane == 0) STOREC(meanacc + g * D + d, sum);
    __syncthreads();  // barrier drains vmcnt: meanacc stores complete
    if (tid == 0)
      s_old = __hip_atomic_fetch_add(doneA + g, 1, __ATOMIC_ACQ_REL,
                                     __HIP_MEMORY_SCOPE_AGENT);
    __syncthreads();
    if (s_old == 31) {  // block-uniform: this block finishes group g
      // count = sum(mask row); 256 threads x 16 ints each
      {
        const int4* mr = (const int4*)(mask + (size_t)g * K);
        int cs = 0;
#pragma unroll
        for (int i = 0; i < 4; ++i) {
          int4 v = mr[tid * 4 + i];
          cs += v.x + v.y + v.z + v.w;
        }
        sm.a.red2[tid] = (float)cs;
      }
      __syncthreads();
      for (int o = 128; o > 0; o >>= 1) {
        if (tid < o) sm.a.red2[tid] += sm.a.red2[tid + o];
        __syncthreads();
      }
      const float cnt = sm.a.red2[0];
      if (tid < D) sm.a.mean_s[tid] = LOADC(meanacc + g * D + tid) / cnt;
      __syncthreads();
      if (tid < D) {
        float q = bq[tid];
        for (int dd = 0; dd < D; ++dd) q += sm.a.mean_s[dd] * Wq[tid * D + dd];
        sm.a.query_s[tid] = q;
      }
      __syncthreads();
      if (tid < D) sm.a.red2[tid] = sm.a.query_s[tid] * bk[tid];
      else sm.a.red2[tid] = 0.f;
      __syncthreads();
      for (int o = 128; o > 0; o >>= 1) {
        if (tid < o) sm.a.red2[tid] += sm.a.red2[tid + o];
        __syncthreads();
      }
      if (tid == 0) STOREC(cvec + g, sm.a.red2[0]);
      if (tid < D) {
        float qq = 0.f;
        for (int dd = 0; dd < D; ++dd) qq += sm.a.query_s[dd] * Wk[dd * D + tid];
        STOREC(qt + g * D + tid, qq);
        STOREC(oacc + g * D + tid, 0.0f);  // zero B's atomic targets
      }
      if (tid == 0) STOREC(denomv + g, 0.0f);
      __syncthreads();  // drain everything above
      if (tid == 0)
        __hip_atomic_store(ready + g, 1, __ATOMIC_RELEASE,
                           __HIP_MEMORY_SCOPE_AGENT);
    }
  }

  // ---------------- Phase B: fused logits + exp + pool
  for (;;) {
    __syncthreads();
    if (tid == 0)
      s_claim = __hip_atomic_fetch_add(ctrB, 1, __ATOMIC_ACQ_REL,
                                       __HIP_MEMORY_SCOPE_AGENT);
    __syncthreads();
    const int item = s_claim;
    if (item >= ITEMS_B) break;
    const int g = item >> 6, k0 = (item & 63) * CK;
    if (tid == 0) {
      while (__hip_atomic_load(ready + g, __ATOMIC_ACQUIRE,
                               __HIP_MEMORY_SCOPE_AGENT) == 0)
        __builtin_amdgcn_s_sleep(8);
      s_cv = LOADC(cvec + g);
    }
    __syncthreads();
    if (tid < D) sm.b.qs[tid] = LOADC(qt + g * D + tid);
    const float4* xg = (const float4*)(x + (size_t)g * D * K + k0);
    for (int i = tid; i < D * (CK / 4); i += 256) {
      int dd = i >> 4, j = i & 15;
      float4 v = xg[(size_t)dd * (K / 4) + j];
      sm.b.xs[dd][4 * j + 0] = v.x;
      sm.b.xs[dd][4 * j + 1] = v.y;
      sm.b.xs[dd][4 * j + 2] = v.z;
      sm.b.xs[dd][4 * j + 3] = v.w;
    }
    __syncthreads();
    {  // logit partials: thread (k = tid&63, part p = tid>>6) sums 32 d's
      const int k = tid & 63, p = tid >> 6;
      float sp = 0.f;
#pragma unroll 8
      for (int dd = p * 32; dd < p * 32 + 32; ++dd)
        sp += sm.b.qs[dd] * sm.b.xs[dd][k];
      sm.b.part_l[p][k] = sp;
    }
    __syncthreads();
    if (tid < CK) {  // combine, exp, mask; reduce denom partial
      const float scale = 0.08838834764831845f;  // 1/sqrt(128)
      float l = (sm.b.part_l[0][tid] + sm.b.part_l[1][tid] +
                 sm.b.part_l[2][tid] + sm.b.part_l[3][tid] + s_cv) * scale;
      float w = mask[(size_t)g * K + k0 + tid] ? __expf(l) : 0.f;
      sm.b.wsm[tid] = w;
#pragma unroll
      for (int o = 32; o > 0; o >>= 1) w += __shfl_down(w, o, 64);
      if (tid == 0) atomicAdd(denomv + g, w);
    }
    __syncthreads();
    {  // pool: thread (d = tid&127, half h = tid>>7) over 32 k's
      const int dd = tid & 127, h = tid >> 7;
      float a2 = 0.f;
#pragma unroll 8
      for (int i = h * 32; i < h * 32 + 32; ++i)
        a2 += sm.b.wsm[i] * sm.b.xs[dd][i];
      sm.b.red[tid] = a2;
    }
    __syncthreads();
    if (tid < D) atomicAdd(oacc + g * D + tid, sm.b.red[tid] + sm.b.red[tid + 128]);
    __syncthreads();  // drain atomics before doneB
    if (tid == 0)
      s_old = __hip_atomic_fetch_add(doneB + g, 1, __ATOMIC_ACQ_REL,
                                     __HIP_MEMORY_SCOPE_AGENT);
    __syncthreads();
    if (s_old == 63) {  // last chunk of group g: finalize output
      if (tid < D) {
        float o = LOADC(oacc + g * D + tid);
        float den = LOADC(denomv + g);
        out[g * D + tid] = o / den;
      }
    }
  }
}

extern "C" void kernel_launch(void* const* d_in, const int* in_sizes, int n_in,
                              void* d_out, int out_size, void* d_ws,
                              size_t ws_size, hipStream_t stream) {
  const float* x = (const float*)d_in[0];
  const int* mask = (const int*)d_in[1];
  const float* Wq = (const float*)d_in[2];
  const float* bq = (const float*)d_in[3];
  const float* Wk = (const float*)d_in[4];
  const float* bk = (const float*)d_in[5];
  float* out = (float*)d_out;

  float* ws = (float*)d_ws;
  float* meanacc = ws;                // G*D
  float* qt = ws + G * D;             // G*D
  float* cvec = ws + 2 * G * D;       // G
  float* oacc = ws + 2 * G * D + G;   // G*D
  float* denomv = ws + 3 * G * D + G; // G
  int* ctrl = (int*)(ws + 3 * G * D + 2 * G);  // 3*G+2 ints

  // zero the control block (flags/counters); data arrays need no init
  hipMemsetAsync(ctrl, 0, (3 * G + 2) * sizeof(int), stream);

  int perCU = 0;
  hipOccupancyMaxActiveBlocksPerMultiprocessor(&perCU, (const void*)fused_all,
                                               256, 0);
  if (perCU < 1) perCU = 1;
  int grid = perCU * 256;
  if (grid > NBLK_MAX) grid = NBLK_MAX;

  void* args[] = {(void*)&x,    (void*)&mask, (void*)&Wq,     (void*)&bq,
                  (void*)&Wk,   (void*)&bk,   (void*)&meanacc, (void*)&qt,
                  (void*)&cvec, (void*)&oacc, (void*)&denomv, (void*)&ctrl,
                  (void*)&out};
  hipLaunchCooperativeKernel((const void*)fused_all, dim3(grid), dim3(256),
                             args, 0, stream);
}

// Round 6
// 807.312 us; speedup vs baseline: 1.9220x; 1.9220x over previous
//
#include <hip/hip_runtime.h>
#include <math.h>

// B=8, N=16, D=128, H=W=64 -> G=128 groups, K=4096 tokens/group.
// keys GEMM collapses: attn_k = q_tilde.x_k + c, q_tilde = Wk^T(Wq mean+bq),
// c = query.bk. Logits ~ +-1 -> no-max softmax safe. Two x passes; pass 2 is
// L3-served (measured R5: FETCH 270 MB for 512 MB logical reads).
//
// Structure (R6): two kernels.
//  kA: per-(g,s) masked-mean chunk; last-finisher block of each group (ONE
//      agent-scope ACQ_REL RMW per block -- per-element fences were the R5
//      disaster) computes count/mean/query/qt/cvec inline, zeroes kB targets.
//  kB: per-(g,c) fused logit+exp+pool; last-finisher block divides out.
#define G 128
#define D 128
#define K 4096
#define CK 64

__global__ __launch_bounds__(256) void kA(
    const float* __restrict__ x, const int* __restrict__ mask,
    const float* __restrict__ Wq, const float* __restrict__ bq,
    const float* __restrict__ Wk, const float* __restrict__ bk,
    float* __restrict__ meanacc, float* __restrict__ qt,
    float* __restrict__ cvec, float* __restrict__ oacc,
    float* __restrict__ denomv, int* __restrict__ doneA) {
  __shared__ float mf[K];  // mask row as float (16 KB), shared by 4 waves
  __shared__ float red[256];
  __shared__ float mean_s[D], query_s[D];
  __shared__ int s_old;
  const int g = blockIdx.x >> 5, s = blockIdx.x & 31;
  const int tid = threadIdx.x;
  if (s == 0) {  // zero kB's atomic targets (visible at kernel boundary)
    if (tid < D) oacc[g * D + tid] = 0.0f;
    if (tid == D) denomv[g] = 0.0f;
  }
  const int4* m4 = (const int4*)(mask + (size_t)g * K);
  for (int i = tid; i < K / 4; i += 256) {
    int4 mi = m4[i];
    *(float4*)&mf[4 * i] =
        make_float4((float)mi.x, (float)mi.y, (float)mi.z, (float)mi.w);
  }
  __syncthreads();
  const int wid = tid >> 6, lane = tid & 63;
  const int d = s * 4 + wid;  // one d-row per wave
  const float4* x4 = (const float4*)(x + ((size_t)g * D + d) * K);
  const float4* mf4 = (const float4*)mf;
  float4 acc = make_float4(0.f, 0.f, 0.f, 0.f);
#pragma unroll
  for (int it = 0; it < K / 256; ++it) {  // 16 iterations
    float4 a = x4[it * 64 + lane];
    float4 m = mf4[it * 64 + lane];
    acc.x += a.x * m.x;
    acc.y += a.y * m.y;
    acc.z += a.z * m.z;
    acc.w += a.w * m.w;
  }
  float sum = acc.x + acc.y + acc.z + acc.w;
#pragma unroll
  for (int o = 32; o > 0; o >>= 1) sum += __shfl_down(sum, o, 64);
  if (lane == 0) meanacc[g * D + d] = sum;  // plain store
  __syncthreads();  // barrier drains vmcnt: stores issued & through L1
  if (tid == 0)     // release: write back this XCD's L2; acquire: invalidate
    s_old = __hip_atomic_fetch_add(doneA + g, 1, __ATOMIC_ACQ_REL,
                                   __HIP_MEMORY_SCOPE_AGENT);
  __syncthreads();
  if (s_old == 31) {  // block-uniform: last finisher does inline k2
    float cs = 0.f;   // count from mf (stride-1 across lanes: conflict-free)
#pragma unroll
    for (int i = 0; i < 16; ++i) cs += mf[i * 256 + tid];
    red[tid] = cs;
    __syncthreads();
    for (int o = 128; o > 0; o >>= 1) {
      if (tid < o) red[tid] += red[tid + o];
      __syncthreads();
    }
    const float cnt = red[0];
    if (tid < D) mean_s[tid] = meanacc[g * D + tid] / cnt;  // plain (post-acq)
    __syncthreads();
    if (tid < D) {
      float q = bq[tid];
      for (int dd = 0; dd < D; ++dd) q += mean_s[dd] * Wq[tid * D + dd];
      query_s[tid] = q;
    }
    __syncthreads();
    red[tid] = (tid < D) ? query_s[tid] * bk[tid] : 0.f;
    __syncthreads();
    for (int o = 128; o > 0; o >>= 1) {
      if (tid < o) red[tid] += red[tid + o];
      __syncthreads();
    }
    if (tid == 0) cvec[g] = red[0];
    if (tid < D) {
      float qq = 0.f;
      for (int dd = 0; dd < D; ++dd) qq += query_s[dd] * Wk[dd * D + tid];
      qt[g * D + tid] = qq;  // kernel boundary publishes to kB
    }
  }
}

// kB: fused logits + exp + pool (+ finalize). Block = (g, 64-k chunk).
// x chunk staged in LDS (row stride 65 == 1 mod 32: every phase conflict-free).
__global__ __launch_bounds__(256) void kB(
    const float* __restrict__ x, const int* __restrict__ mask,
    const float* __restrict__ qt, const float* __restrict__ cvec,
    float* __restrict__ oacc, float* __restrict__ denomv,
    int* __restrict__ doneB, float* __restrict__ out) {
  __shared__ float xs[D][CK + 1];
  __shared__ float qs[D];
  __shared__ float part_l[4][CK];
  __shared__ float wsm[CK];
  __shared__ float red[256];
  __shared__ int s_old;
  const int g = blockIdx.x >> 6;
  const int k0 = (blockIdx.x & 63) * CK;
  const int tid = threadIdx.x;
  if (tid < D) qs[tid] = qt[g * D + tid];
  const float4* xg = (const float4*)(x + (size_t)g * D * K + k0);
  for (int i = tid; i < D * (CK / 4); i += 256) {  // 8 float4 loads/thread
    int dd = i >> 4, j = i & 15;
    float4 v = xg[(size_t)dd * (K / 4) + j];
    xs[dd][4 * j + 0] = v.x;
    xs[dd][4 * j + 1] = v.y;
    xs[dd][4 * j + 2] = v.z;
    xs[dd][4 * j + 3] = v.w;
  }
  __syncthreads();
  {  // logit partials: thread (k = tid&63, part p = tid>>6) sums 32 d's
    const int k = tid & 63, p = tid >> 6;
    float sp = 0.f;
#pragma unroll 8
    for (int dd = p * 32; dd < p * 32 + 32; ++dd) sp += qs[dd] * xs[dd][k];
    part_l[p][k] = sp;
  }
  __syncthreads();
  if (tid < CK) {  // combine, exp, mask; reduce denom partial
    const float scale = 0.08838834764831845f;  // 1/sqrt(128)
    float l = (part_l[0][tid] + part_l[1][tid] + part_l[2][tid] +
               part_l[3][tid] + cvec[g]) * scale;
    float w = mask[(size_t)g * K + k0 + tid] ? __expf(l) : 0.f;
    wsm[tid] = w;
#pragma unroll
    for (int o = 32; o > 0; o >>= 1) w += __shfl_down(w, o, 64);
    if (tid == 0) atomicAdd(denomv + g, w);
  }
  __syncthreads();
  {  // pool: thread (d = tid&127, half h = tid>>7) over 32 k's
    const int dd = tid & 127, h = tid >> 7;
    float a2 = 0.f;
#pragma unroll 8
    for (int i = h * 32; i < h * 32 + 32; ++i) a2 += wsm[i] * xs[dd][i];
    red[tid] = a2;
  }
  __syncthreads();
  if (tid < D)
    atomicAdd(oacc + g * D + tid, red[tid] + red[tid + 128]);
  __syncthreads();  // drains vmcnt: atomics executed at coherence point
  if (tid == 0)
    s_old = __hip_atomic_fetch_add(doneB + g, 1, __ATOMIC_ACQ_REL,
                                   __HIP_MEMORY_SCOPE_AGENT);
  __syncthreads();
  if (s_old == 63) {  // last chunk of group g finalizes the output row
    if (tid < D) out[g * D + tid] = oacc[g * D + tid] / denomv[g];
  }
}

extern "C" void kernel_launch(void* const* d_in, const int* in_sizes, int n_in,
                              void* d_out, int out_size, void* d_ws,
                              size_t ws_size, hipStream_t stream) {
  const float* x = (const float*)d_in[0];
  const int* mask = (const int*)d_in[1];
  const float* Wq = (const float*)d_in[2];
  const float* bq = (const float*)d_in[3];
  const float* Wk = (const float*)d_in[4];
  const float* bk = (const float*)d_in[5];
  float* out = (float*)d_out;

  float* ws = (float*)d_ws;
  float* meanacc = ws;                 // G*D
  float* qt = ws + G * D;              // G*D
  float* cvec = ws + 2 * G * D;        // G
  float* oacc = ws + 2 * G * D + G;    // G*D
  float* denomv = ws + 3 * G * D + G;  // G
  int* doneA = (int*)(ws + 3 * G * D + 2 * G);  // G
  int* doneB = doneA + G;                       // G

  hipMemsetAsync(doneA, 0, 2 * G * sizeof(int), stream);
  kA<<<G * 32, 256, 0, stream>>>(x, mask, Wq, bq, Wk, bk, meanacc, qt, cvec,
                                 oacc, denomv, doneA);
  kB<<<G * 64, 256, 0, stream>>>(x, mask, qt, cvec, oacc, denomv, doneB, out);
}

// Round 7
// 436.277 us; speedup vs baseline: 3.5566x; 1.8505x over previous
//
#include <hip/hip_runtime.h>
#include <math.h>

// B=8, N=16, D=128, H=W=64 -> G=128 groups, K=4096 tokens/group.
// keys GEMM collapses: attn_k = q_tilde.x_k + c, q_tilde = Wk^T(Wq mean+bq),
// c = query.bk. Logits ~ +-1 -> no-max softmax safe. Two x passes; measured
// (R6): pass 1 fetches ~140 MB, pass 2 ~132 MB (L3 serves the rest).
//
// HARD-WON RULE (R5: 1238us, R6: 650us vs R4: ~136us kernel time): NO
// agent-scope acquire/release fences -- they L2-writeback/invalidate per use
// on non-coherent XCD L2s. All cross-block dataflow via kernel boundaries;
// only relaxed atomicAdd within a kernel.
#define G 128
#define D 128
#define K 4096
#define CK 64

// k1: meanacc[g][d] = sum_k mask[g][k]*x[g][d][k].  One wave per d-row,
// 16 float4 x-loads fma'd against int4 mask loads (L1-shared by the 4 waves).
// No LDS -> occupancy at wave cap. Block s==0 zeroes k3's atomic targets.
__global__ __launch_bounds__(256) void k1_mean(const float* __restrict__ x,
                                               const int* __restrict__ mask,
                                               float* __restrict__ meanacc,
                                               float* __restrict__ oacc,
                                               float* __restrict__ denomv) {
  const int g = blockIdx.x >> 5, s = blockIdx.x & 31;
  const int tid = threadIdx.x;
  if (s == 0) {  // visible to k3 via kernel boundary
    if (tid < D) oacc[g * D + tid] = 0.0f;
    if (tid == D) denomv[g] = 0.0f;
  }
  const int wid = tid >> 6, lane = tid & 63;
  const int d = s * 4 + wid;
  const float4* x4 = (const float4*)(x + ((size_t)g * D + d) * K);
  const int4* m4 = (const int4*)(mask + (size_t)g * K);
  float4 acc = make_float4(0.f, 0.f, 0.f, 0.f);
#pragma unroll
  for (int it = 0; it < K / 256; ++it) {  // 16 iterations
    float4 a = x4[it * 64 + lane];
    int4 mi = m4[it * 64 + lane];
    acc.x += a.x * (float)mi.x;
    acc.y += a.y * (float)mi.y;
    acc.z += a.z * (float)mi.z;
    acc.w += a.w * (float)mi.w;
  }
  float sum = acc.x + acc.y + acc.z + acc.w;
#pragma unroll
  for (int o = 32; o > 0; o >>= 1) sum += __shfl_down(sum, o, 64);
  if (lane == 0) meanacc[g * D + d] = sum;
}

// k2: per group: cnt, mean, query = Wq*mean+bq, qt = Wk^T query, c = query.bk
__global__ __launch_bounds__(128) void k2_query(
    const float* __restrict__ meanacc, const int* __restrict__ mask,
    const float* __restrict__ Wq, const float* __restrict__ bq,
    const float* __restrict__ Wk, const float* __restrict__ bk,
    float* __restrict__ qt, float* __restrict__ cvec) {
  __shared__ float mean_s[D], query_s[D], red[D];
  const int g = blockIdx.x, t = threadIdx.x;
  const int4* m4 = (const int4*)(mask + (size_t)g * K);
  int csum = 0;
  for (int i = t; i < K / 4; i += 128) {
    int4 v = m4[i];
    csum += v.x + v.y + v.z + v.w;
  }
  red[t] = (float)csum;
  __syncthreads();
  for (int o = 64; o > 0; o >>= 1) {
    if (t < o) red[t] += red[t + o];
    __syncthreads();
  }
  const float cnt = red[0];
  mean_s[t] = meanacc[g * D + t] / cnt;
  __syncthreads();
  float q = bq[t];
  for (int d = 0; d < D; ++d) q += mean_s[d] * Wq[t * D + d];
  query_s[t] = q;
  __syncthreads();
  red[t] = q * bk[t];
  __syncthreads();
  for (int o = 64; o > 0; o >>= 1) {
    if (t < o) red[t] += red[t + o];
    __syncthreads();
  }
  if (t == 0) cvec[g] = red[0];
  float qq = 0.f;
  for (int d = 0; d < D; ++d) qq += query_s[d] * Wk[d * D + t];
  qt[g * D + t] = qq;
}

// k3: fused logits + exp + pool. Block = (g, 64-k chunk).
// Staging loop ALSO accumulates logit partials in registers: thread tid owns
// k-quad 4*(tid&15)..+3 and d-rows (tid>>4)+16*it (it=0..7); qt values come
// straight from global (512 B/group, L1-hot across the group's 64 blocks).
// xs rows stride 65 (==1 mod 32): pool-phase reads conflict-free.
__global__ __launch_bounds__(256) void k3_fused(
    const float* __restrict__ x, const int* __restrict__ mask,
    const float* __restrict__ qt, const float* __restrict__ cvec,
    float* __restrict__ oacc, float* __restrict__ denomv) {
  __shared__ float xs[D][CK + 1];
  __shared__ float part2[CK][17];  // [k][owner], both phases 2 lanes/bank
  __shared__ float wsm[CK];
  __shared__ float red[256];
  const int g = blockIdx.x >> 6;
  const int k0 = (blockIdx.x & 63) * CK;
  const int tid = threadIdx.x;
  const float4* xg = (const float4*)(x + (size_t)g * D * K + k0);
  const int j = tid & 15, owner = tid >> 4;  // k-quad 4j..4j+3
  float p0 = 0.f, p1 = 0.f, p2 = 0.f, p3 = 0.f;
#pragma unroll
  for (int it = 0; it < 8; ++it) {
    const int dd = owner + 16 * it;
    float4 v = xg[(size_t)dd * (K / 4) + j];
    float qv = qt[g * D + dd];  // L1-hot scalar
    xs[dd][4 * j + 0] = v.x;
    xs[dd][4 * j + 1] = v.y;
    xs[dd][4 * j + 2] = v.z;
    xs[dd][4 * j + 3] = v.w;
    p0 += qv * v.x;
    p1 += qv * v.y;
    p2 += qv * v.z;
    p3 += qv * v.w;
  }
  part2[4 * j + 0][owner] = p0;
  part2[4 * j + 1][owner] = p1;
  part2[4 * j + 2][owner] = p2;
  part2[4 * j + 3][owner] = p3;
  __syncthreads();
  if (tid < CK) {  // combine 16 partials, exp, mask; reduce denom partial
    float l = 0.f;
#pragma unroll
    for (int o = 0; o < 16; ++o) l += part2[tid][o];
    const float scale = 0.08838834764831845f;  // 1/sqrt(128)
    l = (l + cvec[g]) * scale;
    float w = mask[(size_t)g * K + k0 + tid] ? __expf(l) : 0.f;
    wsm[tid] = w;
#pragma unroll
    for (int o = 32; o > 0; o >>= 1) w += __shfl_down(w, o, 64);
    if (tid == 0) atomicAdd(denomv + g, w);
  }
  __syncthreads();
  {  // pool: thread (d = tid&127, half h = tid>>7) over 32 k's
    const int dd = tid & 127, h = tid >> 7;
    float a2 = 0.f;
#pragma unroll 8
    for (int i = h * 32; i < h * 32 + 32; ++i) a2 += wsm[i] * xs[dd][i];
    red[tid] = a2;
  }
  __syncthreads();
  if (tid < D) atomicAdd(oacc + g * D + tid, red[tid] + red[tid + 128]);
}

// k4: out = oacc / denom
__global__ __launch_bounds__(256) void k4_norm(const float* __restrict__ oacc,
                                               const float* __restrict__ denomv,
                                               float* __restrict__ out) {
  int i = blockIdx.x * 256 + threadIdx.x;  // exactly G*D
  out[i] = oacc[i] / denomv[i >> 7];
}

extern "C" void kernel_launch(void* const* d_in, const int* in_sizes, int n_in,
                              void* d_out, int out_size, void* d_ws,
                              size_t ws_size, hipStream_t stream) {
  const float* x = (const float*)d_in[0];
  const int* mask = (const int*)d_in[1];
  const float* Wq = (const float*)d_in[2];
  const float* bq = (const float*)d_in[3];
  const float* Wk = (const float*)d_in[4];
  const float* bk = (const float*)d_in[5];
  float* out = (float*)d_out;

  float* ws = (float*)d_ws;
  float* meanacc = ws;                 // G*D
  float* qt = ws + G * D;              // G*D
  float* cvec = ws + 2 * G * D;        // G
  float* oacc = ws + 2 * G * D + G;    // G*D
  float* denomv = ws + 3 * G * D + G;  // G

  k1_mean<<<G * 32, 256, 0, stream>>>(x, mask, meanacc, oacc, denomv);
  k2_query<<<G, 128, 0, stream>>>(meanacc, mask, Wq, bq, Wk, bk, qt, cvec);
  k3_fused<<<G * (K / CK), 256, 0, stream>>>(x, mask, qt, cvec, oacc, denomv);
  k4_norm<<<(G * D) / 256, 256, 0, stream>>>(oacc, denomv, out);
}